// Round 1
// baseline (630.254 us; speedup 1.0000x reference)
//
#include <hip/hip_runtime.h>
#include <stdint.h>
#include <stddef.h>

#define M_TOK 8192
#define N_OUT 4096
#define K_IN  4096
#define R_LORA 16
#define BM 128
#define BN 128
#define BK 32

typedef __bf16 bf16_t;
typedef __bf16 bf16x8 __attribute__((ext_vector_type(8)));
typedef float floatx4 __attribute__((ext_vector_type(4)));

// async global->LDS, 16B per lane. LDS dest must be wave-uniform base; HW adds lane*16.
__device__ inline void async_copy16(const bf16_t* g, bf16_t* l) {
  __builtin_amdgcn_global_load_lds(
      (__attribute__((address_space(1))) void*)(uintptr_t)(const void*)g,
      (__attribute__((address_space(3))) void*)l,
      16, 0, 0);
}

// ---------------- pass 1a: cast x (fp32) -> bf16 ----------------
__global__ __launch_bounds__(256) void cast_x_kernel(const float* __restrict__ x,
                                                     bf16_t* __restrict__ xb) {
  size_t i = (size_t)blockIdx.x * 256 + threadIdx.x;  // one 8-elem chunk per thread
  const float4* p = (const float4*)x + i * 2;
  float4 a = p[0], b = p[1];
  bf16x8 v;
  v[0] = (bf16_t)a.x; v[1] = (bf16_t)a.y; v[2] = (bf16_t)a.z; v[3] = (bf16_t)a.w;
  v[4] = (bf16_t)b.x; v[5] = (bf16_t)b.y; v[6] = (bf16_t)b.z; v[7] = (bf16_t)b.w;
  *(bf16x8*)(xb + i * 8) = v;
}

// ---------------- pass 1b: Weff = W + scale * B@A, cast -> bf16 ----------------
__global__ __launch_bounds__(256) void make_weff(const float* __restrict__ W,
                                                 const float* __restrict__ lB,
                                                 const float* __restrict__ lA,
                                                 const float* __restrict__ scale_p,
                                                 bf16_t* __restrict__ wb) {
  const int o = blockIdx.x;  // output row, 0..4095
  __shared__ float Brow[R_LORA];
  if (threadIdx.x < R_LORA)
    Brow[threadIdx.x] = lB[(size_t)o * R_LORA + threadIdx.x] * (*scale_p);
  __syncthreads();
#pragma unroll
  for (int cc = 0; cc < 2; ++cc) {
    int i0 = (cc * 256 + (int)threadIdx.x) * 8;
    const float* wp = W + (size_t)o * K_IN + i0;
    float acc[8];
    float4 w0 = *(const float4*)wp;
    float4 w1 = *(const float4*)(wp + 4);
    acc[0] = w0.x; acc[1] = w0.y; acc[2] = w0.z; acc[3] = w0.w;
    acc[4] = w1.x; acc[5] = w1.y; acc[6] = w1.z; acc[7] = w1.w;
#pragma unroll
    for (int r = 0; r < R_LORA; ++r) {
      float b = Brow[r];
      const float* ap = lA + (size_t)r * K_IN + i0;
      float4 a0 = *(const float4*)ap;
      float4 a1 = *(const float4*)(ap + 4);
      acc[0] += b * a0.x; acc[1] += b * a0.y; acc[2] += b * a0.z; acc[3] += b * a0.w;
      acc[4] += b * a1.x; acc[5] += b * a1.y; acc[6] += b * a1.z; acc[7] += b * a1.w;
    }
    bf16x8 v;
#pragma unroll
    for (int j = 0; j < 8; ++j) v[j] = (bf16_t)acc[j];
    *(bf16x8*)(wb + (size_t)o * K_IN + i0) = v;
  }
}

// ---------------- pass 2: C = A @ Bw^T + bias (bf16 MFMA, m97 structure) ----------------
// A: [M,K] bf16 row-major (x), Bw: [N,K] bf16 row-major (Weff), C fp32 [M,N]
__global__ __launch_bounds__(256) void gemm_bt(const bf16_t* __restrict__ A,
                                               const bf16_t* __restrict__ Bw,
                                               const float* __restrict__ bias,
                                               float* __restrict__ C) {
  __shared__ bf16_t sA[BM * BK];  // 8 KB, row-major, row stride BK (no pad: global_load_lds)
  __shared__ bf16_t sB[BN * BK];  // 8 KB

  const int tid  = threadIdx.x;
  const int wave = tid >> 6;
  const int lane = tid & 63;
  const int lr   = lane & 15;
  const int quad = lane >> 4;
  const int bm = blockIdx.y * BM;
  const int bn = blockIdx.x * BN;
  const int wm = (wave >> 1) * 64;  // wave's 64x64 sub-tile
  const int wn = (wave & 1) * 64;

  // Staging: 16B chunk c -> LDS elems [c*8, c*8+8), row = c>>2, k-offset = (c&3)*8.
  // Inst j (j=0,1): chunks c = j*256 + wave*64 + lane.
  const int c0  = wave * 64 + lane;
  const int rA0 = c0 >> 2;            // 0..63
  const int kc  = (lane & 3) * 8;
  const bf16_t* gA0 = A  + (size_t)(bm + rA0) * K_IN + kc;
  const bf16_t* gA1 = A  + (size_t)(bm + 64 + rA0) * K_IN + kc;
  const bf16_t* gB0 = Bw + (size_t)(bn + rA0) * K_IN + kc;
  const bf16_t* gB1 = Bw + (size_t)(bn + 64 + rA0) * K_IN + kc;
  bf16_t* lA0 = sA + wave * 512;         // wave-uniform LDS bases
  bf16_t* lA1 = sA + 2048 + wave * 512;
  bf16_t* lB0 = sB + wave * 512;
  bf16_t* lB1 = sB + 2048 + wave * 512;

  // Fragment read pointers (iteration-invariant): A[m=lr][k=quad*8+j] per 16x16 tile
  const bf16_t* fA[4];
  const bf16_t* fB[4];
#pragma unroll
  for (int i = 0; i < 4; ++i) {
    fA[i] = sA + (wm + i * 16 + lr) * BK + quad * 8;
    fB[i] = sB + (wn + i * 16 + lr) * BK + quad * 8;
  }

  floatx4 acc[4][4];
#pragma unroll
  for (int i = 0; i < 4; ++i)
#pragma unroll
    for (int j = 0; j < 4; ++j) acc[i][j] = {0.f, 0.f, 0.f, 0.f};

  for (int k0 = 0; k0 < K_IN; k0 += BK) {
    __syncthreads();  // previous compute done before overwriting LDS
    async_copy16(gA0, lA0);
    async_copy16(gA1, lA1);
    async_copy16(gB0, lB0);
    async_copy16(gB1, lB1);
    gA0 += BK; gA1 += BK; gB0 += BK; gB1 += BK;
    __syncthreads();  // compiler drains vmcnt(0) before s_barrier

    bf16x8 a[4], b[4];
#pragma unroll
    for (int i = 0; i < 4; ++i) {
      a[i] = *(const bf16x8*)fA[i];
      b[i] = *(const bf16x8*)fB[i];
    }
#pragma unroll
    for (int i = 0; i < 4; ++i)
#pragma unroll
      for (int j = 0; j < 4; ++j)
        acc[i][j] = __builtin_amdgcn_mfma_f32_16x16x32_bf16(a[i], b[j], acc[i][j], 0, 0, 0);
  }

  // Epilogue: C[row][col], row = (quad*4 + reg) from A-side, col = lr from B-side
#pragma unroll
  for (int j = 0; j < 4; ++j) {
    int col = bn + wn + j * 16 + lr;
    float bb = bias[col];
#pragma unroll
    for (int i = 0; i < 4; ++i) {
      int row0 = bm + wm + i * 16 + quad * 4;
      floatx4 v = acc[i][j];
#pragma unroll
      for (int r = 0; r < 4; ++r)
        C[(size_t)(row0 + r) * N_OUT + col] = v[r] + bb;
    }
  }
}

// ---------------- fallback (workspace too small): fp32 path ----------------
// t[m,r] = scale * sum_k x[m,k]*A[r,k]
__global__ __launch_bounds__(256) void lora_xa(const float* __restrict__ x,
                                               const float* __restrict__ lA,
                                               const float* __restrict__ scale_p,
                                               float* __restrict__ t) {
  int m = blockIdx.x;
  int r = threadIdx.x & 15;
  int kcn = threadIdx.x >> 4;  // 16 k-chunks of 256
  float acc = 0.f;
  const float* xr = x + (size_t)m * K_IN + kcn * 256;
  const float* ar = lA + (size_t)r * K_IN + kcn * 256;
  for (int k = 0; k < 256; k += 4) {
    float4 xv = *(const float4*)(xr + k);
    float4 av = *(const float4*)(ar + k);
    acc += xv.x * av.x + xv.y * av.y + xv.z * av.z + xv.w * av.w;
  }
  __shared__ float s[256];
  s[threadIdx.x] = acc;
  __syncthreads();
  if (threadIdx.x < 16) {
    float v = 0.f;
    for (int i = 0; i < 16; ++i) v += s[threadIdx.x + i * 16];
    t[(size_t)m * 16 + threadIdx.x] = v * (*scale_p);
  }
}

__global__ __launch_bounds__(256) void gemm_f32_fb(const float* __restrict__ X,
                                                   const float* __restrict__ W,
                                                   const float* __restrict__ bias,
                                                   const float* __restrict__ t,
                                                   const float* __restrict__ lB,
                                                   float* __restrict__ C) {
  __shared__ float sX[64][17];
  __shared__ float sW[64][17];
  int tid = threadIdx.x;
  int tx = tid & 15, ty = tid >> 4;
  int m0 = blockIdx.y * 64, n0 = blockIdx.x * 64;
  int lrow = tid >> 2, lcol = (tid & 3) * 4;
  float acc[4][4] = {};
  for (int k0 = 0; k0 < K_IN; k0 += 16) {
    __syncthreads();
    float4 xv = *(const float4*)(X + (size_t)(m0 + lrow) * K_IN + k0 + lcol);
    float4 wv = *(const float4*)(W + (size_t)(n0 + lrow) * K_IN + k0 + lcol);
    sX[lrow][lcol + 0] = xv.x; sX[lrow][lcol + 1] = xv.y;
    sX[lrow][lcol + 2] = xv.z; sX[lrow][lcol + 3] = xv.w;
    sW[lrow][lcol + 0] = wv.x; sW[lrow][lcol + 1] = wv.y;
    sW[lrow][lcol + 2] = wv.z; sW[lrow][lcol + 3] = wv.w;
    __syncthreads();
#pragma unroll
    for (int kk = 0; kk < 16; ++kk) {
      float xr[4], wr[4];
#pragma unroll
      for (int i = 0; i < 4; ++i) { xr[i] = sX[ty * 4 + i][kk]; wr[i] = sW[tx * 4 + i][kk]; }
#pragma unroll
      for (int i = 0; i < 4; ++i)
#pragma unroll
        for (int j = 0; j < 4; ++j) acc[i][j] += xr[i] * wr[j];
    }
  }
  for (int j = 0; j < 4; ++j) {
    int n = n0 + tx * 4 + j;
    float bb = bias[n];
    for (int i = 0; i < 4; ++i) {
      int m = m0 + ty * 4 + i;
      float l = 0.f;
      for (int r = 0; r < R_LORA; ++r) l += t[(size_t)m * 16 + r] * lB[(size_t)n * 16 + r];
      C[(size_t)m * N_OUT + n] = acc[i][j] + bb + l;
    }
  }
}

extern "C" void kernel_launch(void* const* d_in, const int* in_sizes, int n_in,
                              void* d_out, int out_size, void* d_ws, size_t ws_size,
                              hipStream_t stream) {
  const float* x     = (const float*)d_in[0];
  const float* W     = (const float*)d_in[1];
  const float* bias  = (const float*)d_in[2];
  const float* lB    = (const float*)d_in[3];
  const float* lA    = (const float*)d_in[4];
  const float* scale = (const float*)d_in[5];
  float* out = (float*)d_out;

  const size_t x_bytes = (size_t)M_TOK * K_IN * sizeof(bf16_t);  // 64 MB
  const size_t w_bytes = (size_t)N_OUT * K_IN * sizeof(bf16_t);  // 32 MB

  if (ws_size >= x_bytes + w_bytes) {
    bf16_t* xb = (bf16_t*)d_ws;
    bf16_t* wb = (bf16_t*)((char*)d_ws + x_bytes);
    cast_x_kernel<<<(M_TOK * (K_IN / 8)) / 256, 256, 0, stream>>>(x, xb);
    make_weff<<<N_OUT, 256, 0, stream>>>(W, lB, lA, scale, wb);
    gemm_bt<<<dim3(N_OUT / BN, M_TOK / BM), 256, 0, stream>>>(xb, wb, bias, out);
  } else {
    // fp32 fallback: out = x@W^T + bias + (x@A^T*scale)@B^T ; needs 512 KB ws
    float* t = (float*)d_ws;
    lora_xa<<<M_TOK, 256, 0, stream>>>(x, lA, scale, t);
    gemm_f32_fb<<<dim3(N_OUT / 64, M_TOK / 64), 256, 0, stream>>>(x, W, bias, t, lB, out);
  }
}

// Round 2
// 561.795 us; speedup vs baseline: 1.1219x; 1.1219x over previous
//
#include <hip/hip_runtime.h>
#include <stdint.h>
#include <stddef.h>

#define M_TOK 8192
#define N_OUT 4096
#define K_IN  4096
#define R_LORA 16
#define BM 128
#define BN 256
#define BK 32

typedef __bf16 bf16_t;
typedef __bf16 bf16x4 __attribute__((ext_vector_type(4)));
typedef __bf16 bf16x8 __attribute__((ext_vector_type(8)));
typedef float floatx4 __attribute__((ext_vector_type(4)));

// async global->LDS, 16B per lane. LDS dest must be wave-uniform base; HW adds lane*16.
__device__ inline void async_copy16(const bf16_t* g, bf16_t* l) {
  __builtin_amdgcn_global_load_lds(
      (__attribute__((address_space(1))) void*)(uintptr_t)(const void*)g,
      (__attribute__((address_space(3))) void*)l,
      16, 0, 0);
}

// ---------------- pass 1a: cast x (fp32) -> bf16, unit-stride float4 ----------------
__global__ __launch_bounds__(256) void cast_x_kernel(const float* __restrict__ x,
                                                     bf16_t* __restrict__ xb) {
  size_t i = (size_t)blockIdx.x * 256 + threadIdx.x;  // one float4 per thread
  float4 a = ((const float4*)x)[i];
  bf16x4 v;
  v[0] = (bf16_t)a.x; v[1] = (bf16_t)a.y; v[2] = (bf16_t)a.z; v[3] = (bf16_t)a.w;
  *(bf16x4*)(xb + i * 4) = v;
}

// ---------------- pass 1b: Weff = W + scale * B@A, cast -> bf16 ----------------
__global__ __launch_bounds__(256) void make_weff(const float* __restrict__ W,
                                                 const float* __restrict__ lB,
                                                 const float* __restrict__ lA,
                                                 const float* __restrict__ scale_p,
                                                 bf16_t* __restrict__ wb) {
  const int o = blockIdx.x;  // output row, 0..4095
  __shared__ float Brow[R_LORA];
  if (threadIdx.x < R_LORA)
    Brow[threadIdx.x] = lB[(size_t)o * R_LORA + threadIdx.x] * (*scale_p);
  __syncthreads();
  const float4* W4 = (const float4*)(W + (size_t)o * K_IN);
  const float4* A4 = (const float4*)lA;
#pragma unroll
  for (int cc = 0; cc < 4; ++cc) {
    int idx = cc * 256 + (int)threadIdx.x;  // unit-stride float4 per inst
    float4 w = W4[idx];
    float a0 = w.x, a1 = w.y, a2 = w.z, a3 = w.w;
#pragma unroll
    for (int r = 0; r < R_LORA; ++r) {
      float b = Brow[r];
      float4 av = A4[(size_t)r * (K_IN / 4) + idx];
      a0 += b * av.x; a1 += b * av.y; a2 += b * av.z; a3 += b * av.w;
    }
    bf16x4 v;
    v[0] = (bf16_t)a0; v[1] = (bf16_t)a1; v[2] = (bf16_t)a2; v[3] = (bf16_t)a3;
    *(bf16x4*)(wb + (size_t)o * K_IN + (size_t)idx * 4) = v;
  }
}

// ---------------- pass 2: C = A @ Bw^T + bias ----------------
// BM=128 x BN=256 block tile, 4 waves, each wave 64x128 (4x8 of 16x16x32 bf16 MFMA).
// LDS layout per tile: slot s (16B chunks): row = s>>2, k-chunk q = ((s&3) - (row>>1)) & 3
// (k-chunk rotation swizzle: breaks the 64B-row-stride bank pattern; staging stays
//  64B-contiguous per row so global_load_lds coalescing is preserved).
__global__ __launch_bounds__(256, 2) void gemm_bt(const bf16_t* __restrict__ A,
                                                  const bf16_t* __restrict__ Bw,
                                                  const float* __restrict__ bias,
                                                  float* __restrict__ C) {
  __shared__ bf16_t sA[BM * BK];  // 8 KB
  __shared__ bf16_t sB[BN * BK];  // 16 KB

  const int tid  = threadIdx.x;
  const int wave = tid >> 6;
  const int lane = tid & 63;
  const int lr   = lane & 15;
  const int quad = lane >> 4;
  const int bm = blockIdx.y * BM;
  const int bn = blockIdx.x * BN;
  const int wm = (wave >> 1) * 64;   // wave's 64x128 sub-tile
  const int wn = (wave & 1) * 128;

  // ---- staging pointers (iteration-invariant except += BK) ----
  const bf16_t* gA[2];
  const bf16_t* gB[4];
  bf16_t* lA[2];
  bf16_t* lB[4];
#pragma unroll
  for (int i = 0; i < 2; ++i) {
    int s = i * 256 + wave * 64 + lane;
    int row = s >> 2;
    int q = ((s & 3) - (s >> 3)) & 3;            // swizzled k-chunk this lane fetches
    gA[i] = A + (size_t)(bm + row) * K_IN + q * 8;
    lA[i] = sA + (size_t)(i * 256 + wave * 64) * 8;  // wave-uniform base
  }
#pragma unroll
  for (int i = 0; i < 4; ++i) {
    int s = i * 256 + wave * 64 + lane;
    int row = s >> 2;
    int q = ((s & 3) - (s >> 3)) & 3;
    gB[i] = Bw + (size_t)(bn + row) * K_IN + q * 8;
    lB[i] = sB + (size_t)(i * 256 + wave * 64) * 8;
  }

  // ---- fragment read offsets ----
  // frag (row, quad): elem addr = row*32 + ((quad + (row>>1)) & 3)*8.
  // row = (wtile + i*16) + lr with wtile,16 multiples => (row>>1) = const + i*8 + (lr>>1),
  // and i*8 ≡ 0 (mod 4), wtile/2 ≡ 0 (mod 4) => lane-constant chunk offset:
  const int cofs = ((quad + (lr >> 1)) & 3) * 8;
  const bf16_t* fA[4];
  const bf16_t* fB[8];
#pragma unroll
  for (int i = 0; i < 4; ++i) fA[i] = sA + (wm + i * 16 + lr) * 32 + cofs;
#pragma unroll
  for (int j = 0; j < 8; ++j) fB[j] = sB + (wn + j * 16 + lr) * 32 + cofs;

  floatx4 acc[4][8];
#pragma unroll
  for (int i = 0; i < 4; ++i)
#pragma unroll
    for (int j = 0; j < 8; ++j) acc[i][j] = {0.f, 0.f, 0.f, 0.f};

  for (int k0 = 0; k0 < K_IN; k0 += BK) {
    __syncthreads();  // previous compute done before overwriting LDS
    async_copy16(gA[0], lA[0]);
    async_copy16(gA[1], lA[1]);
    async_copy16(gB[0], lB[0]);
    async_copy16(gB[1], lB[1]);
    async_copy16(gB[2], lB[2]);
    async_copy16(gB[3], lB[3]);
    gA[0] += BK; gA[1] += BK;
    gB[0] += BK; gB[1] += BK; gB[2] += BK; gB[3] += BK;
    __syncthreads();  // drains vmcnt(0) before barrier

    bf16x8 a[4], b[8];
#pragma unroll
    for (int i = 0; i < 4; ++i) a[i] = *(const bf16x8*)fA[i];
#pragma unroll
    for (int j = 0; j < 8; ++j) b[j] = *(const bf16x8*)fB[j];
#pragma unroll
    for (int i = 0; i < 4; ++i)
#pragma unroll
      for (int j = 0; j < 8; ++j)
        acc[i][j] = __builtin_amdgcn_mfma_f32_16x16x32_bf16(a[i], b[j], acc[i][j], 0, 0, 0);
  }

  // Epilogue: row = quad*4 + reg (A side), col = lr (B side)
#pragma unroll
  for (int j = 0; j < 8; ++j) {
    int col = bn + wn + j * 16 + lr;
    float bb = bias[col];
#pragma unroll
    for (int i = 0; i < 4; ++i) {
      int row0 = bm + wm + i * 16 + quad * 4;
      floatx4 v = acc[i][j];
#pragma unroll
      for (int r = 0; r < 4; ++r)
        C[(size_t)(row0 + r) * N_OUT + col] = v[r] + bb;
    }
  }
}

// ---------------- fallback (workspace too small): fp32 path ----------------
__global__ __launch_bounds__(256) void lora_xa(const float* __restrict__ x,
                                               const float* __restrict__ lA,
                                               const float* __restrict__ scale_p,
                                               float* __restrict__ t) {
  int m = blockIdx.x;
  int r = threadIdx.x & 15;
  int kcn = threadIdx.x >> 4;
  float acc = 0.f;
  const float* xr = x + (size_t)m * K_IN + kcn * 256;
  const float* ar = lA + (size_t)r * K_IN + kcn * 256;
  for (int k = 0; k < 256; k += 4) {
    float4 xv = *(const float4*)(xr + k);
    float4 av = *(const float4*)(ar + k);
    acc += xv.x * av.x + xv.y * av.y + xv.z * av.z + xv.w * av.w;
  }
  __shared__ float s[256];
  s[threadIdx.x] = acc;
  __syncthreads();
  if (threadIdx.x < 16) {
    float v = 0.f;
    for (int i = 0; i < 16; ++i) v += s[threadIdx.x + i * 16];
    t[(size_t)m * 16 + threadIdx.x] = v * (*scale_p);
  }
}

__global__ __launch_bounds__(256) void gemm_f32_fb(const float* __restrict__ X,
                                                   const float* __restrict__ W,
                                                   const float* __restrict__ bias,
                                                   const float* __restrict__ t,
                                                   const float* __restrict__ lB,
                                                   float* __restrict__ C) {
  __shared__ float sX[64][17];
  __shared__ float sW[64][17];
  int tid = threadIdx.x;
  int tx = tid & 15, ty = tid >> 4;
  int m0 = blockIdx.y * 64, n0 = blockIdx.x * 64;
  int lrow = tid >> 2, lcol = (tid & 3) * 4;
  float acc[4][4] = {};
  for (int k0 = 0; k0 < K_IN; k0 += 16) {
    __syncthreads();
    float4 xv = *(const float4*)(X + (size_t)(m0 + lrow) * K_IN + k0 + lcol);
    float4 wv = *(const float4*)(W + (size_t)(n0 + lrow) * K_IN + k0 + lcol);
    sX[lrow][lcol + 0] = xv.x; sX[lrow][lcol + 1] = xv.y;
    sX[lrow][lcol + 2] = xv.z; sX[lrow][lcol + 3] = xv.w;
    sW[lrow][lcol + 0] = wv.x; sW[lrow][lcol + 1] = wv.y;
    sW[lrow][lcol + 2] = wv.z; sW[lrow][lcol + 3] = wv.w;
    __syncthreads();
#pragma unroll
    for (int kk = 0; kk < 16; ++kk) {
      float xr[4], wr[4];
#pragma unroll
      for (int i = 0; i < 4; ++i) { xr[i] = sX[ty * 4 + i][kk]; wr[i] = sW[tx * 4 + i][kk]; }
#pragma unroll
      for (int i = 0; i < 4; ++i)
#pragma unroll
        for (int j = 0; j < 4; ++j) acc[i][j] += xr[i] * wr[j];
    }
  }
  for (int j = 0; j < 4; ++j) {
    int n = n0 + tx * 4 + j;
    float bb = bias[n];
    for (int i = 0; i < 4; ++i) {
      int m = m0 + ty * 4 + i;
      float l = 0.f;
      for (int r = 0; r < R_LORA; ++r) l += t[(size_t)m * 16 + r] * lB[(size_t)n * 16 + r];
      C[(size_t)m * N_OUT + n] = acc[i][j] + bb + l;
    }
  }
}

extern "C" void kernel_launch(void* const* d_in, const int* in_sizes, int n_in,
                              void* d_out, int out_size, void* d_ws, size_t ws_size,
                              hipStream_t stream) {
  const float* x     = (const float*)d_in[0];
  const float* W     = (const float*)d_in[1];
  const float* bias  = (const float*)d_in[2];
  const float* lB    = (const float*)d_in[3];
  const float* lA    = (const float*)d_in[4];
  const float* scale = (const float*)d_in[5];
  float* out = (float*)d_out;

  const size_t x_bytes = (size_t)M_TOK * K_IN * sizeof(bf16_t);  // 64 MB
  const size_t w_bytes = (size_t)N_OUT * K_IN * sizeof(bf16_t);  // 32 MB

  if (ws_size >= x_bytes + w_bytes) {
    bf16_t* xb = (bf16_t*)d_ws;
    bf16_t* wb = (bf16_t*)((char*)d_ws + x_bytes);
    cast_x_kernel<<<(M_TOK * K_IN / 4) / 256, 256, 0, stream>>>(x, xb);
    make_weff<<<N_OUT, 256, 0, stream>>>(W, lB, lA, scale, wb);
    gemm_bt<<<dim3(N_OUT / BN, M_TOK / BM), 256, 0, stream>>>(xb, wb, bias, out);
  } else {
    float* t = (float*)d_ws;
    lora_xa<<<M_TOK, 256, 0, stream>>>(x, lA, scale, t);
    gemm_f32_fb<<<dim3(N_OUT / 64, M_TOK / 64), 256, 0, stream>>>(x, W, bias, t, lB, out);
  }
}

// Round 3
// 550.740 us; speedup vs baseline: 1.1444x; 1.0201x over previous
//
#include <hip/hip_runtime.h>
#include <stdint.h>
#include <stddef.h>

#define M_TOK 8192
#define N_OUT 4096
#define K_IN  4096
#define R_LORA 16
#define BM 128
#define BN 256
#define BK 32

typedef __bf16 bf16_t;
typedef __bf16 bf16x4 __attribute__((ext_vector_type(4)));
typedef __bf16 bf16x8 __attribute__((ext_vector_type(8)));
typedef float floatx4 __attribute__((ext_vector_type(4)));

// async global->LDS, 16B per lane. LDS dest must be wave-uniform base; HW adds lane*16.
__device__ inline void async_copy16(const bf16_t* g, bf16_t* l) {
  __builtin_amdgcn_global_load_lds(
      (__attribute__((address_space(1))) void*)(uintptr_t)(const void*)g,
      (__attribute__((address_space(3))) void*)l,
      16, 0, 0);
}

// ---------------- pass 1a: cast x (fp32) -> bf16, unit-stride float4 ----------------
__global__ __launch_bounds__(256) void cast_x_kernel(const float* __restrict__ x,
                                                     bf16_t* __restrict__ xb) {
  size_t i = (size_t)blockIdx.x * 256 + threadIdx.x;  // one float4 per thread
  float4 a = ((const float4*)x)[i];
  bf16x4 v;
  v[0] = (bf16_t)a.x; v[1] = (bf16_t)a.y; v[2] = (bf16_t)a.z; v[3] = (bf16_t)a.w;
  *(bf16x4*)(xb + i * 4) = v;
}

// ---------------- pass 1b: Weff = W + scale * B@A, cast -> bf16 ----------------
// v2: block = (K-chunk of 1024) x (32 rows). Each thread keeps its 16x4 slice of
// lora_A in REGISTERS (loaded once); lora_B is a uniform scalar load per row.
// lA traffic: 1 GB (v1, per-row re-read) -> 32 MB total.
__global__ __launch_bounds__(256) void make_weff(const float* __restrict__ W,
                                                 const float* __restrict__ lB,
                                                 const float* __restrict__ lA,
                                                 const float* __restrict__ scale_p,
                                                 bf16_t* __restrict__ wb) {
  const int kbase = blockIdx.x * 1024 + threadIdx.x * 4;  // this thread's 4 k's
  const int o0    = blockIdx.y * 32;
  const float scale = *scale_p;

  float4 areg[R_LORA];
#pragma unroll
  for (int r = 0; r < R_LORA; ++r)
    areg[r] = *(const float4*)(lA + (size_t)r * K_IN + kbase);

  for (int oo = 0; oo < 32; ++oo) {
    const int o = o0 + oo;
    float4 w = *(const float4*)(W + (size_t)o * K_IN + kbase);
    float a0 = w.x, a1 = w.y, a2 = w.z, a3 = w.w;
#pragma unroll
    for (int r = 0; r < R_LORA; ++r) {
      float b = lB[(size_t)o * R_LORA + r] * scale;  // uniform across block -> scalar load
      a0 += b * areg[r].x; a1 += b * areg[r].y;
      a2 += b * areg[r].z; a3 += b * areg[r].w;
    }
    bf16x4 v;
    v[0] = (bf16_t)a0; v[1] = (bf16_t)a1; v[2] = (bf16_t)a2; v[3] = (bf16_t)a3;
    *(bf16x4*)(wb + (size_t)o * K_IN + kbase) = v;
  }
}

// ---------------- pass 2: C = A @ Bw^T + bias ----------------
// BM=128 x BN=256 block tile, 4 waves, each 64x128 (4x8 of 16x16x32 bf16 MFMA).
// k-chunk rotation swizzle (R2: conflicts 3.35e7 -> 0): slot s -> row s>>2,
// chunk ((s&3)-(s>>3))&3; fragment chunk offset ((quad+(lr>>1))&3)*8.
// R3: double-buffered LDS, ONE barrier per K-iter; stage(k+1) issued after the
// barrier so the next barrier's vmcnt(0) drain lands on a load that had a full
// compute phase in flight. Buffer parity folds into ds_read immediate offsets.
__global__ __launch_bounds__(256, 2) void gemm_bt(const bf16_t* __restrict__ A,
                                                  const bf16_t* __restrict__ Bw,
                                                  const float* __restrict__ bias,
                                                  float* __restrict__ C) {
  __shared__ bf16_t sA[2 * BM * BK];  // 16 KB (two 8 KB buffers)
  __shared__ bf16_t sB[2 * BN * BK];  // 32 KB (two 16 KB buffers)

  const int tid  = threadIdx.x;
  const int wave = tid >> 6;
  const int lane = tid & 63;
  const int lr   = lane & 15;
  const int quad = lane >> 4;
  const int bm = blockIdx.y * BM;
  const int bn = blockIdx.x * BN;
  const int wm = (wave >> 1) * 64;   // wave's 64x128 sub-tile
  const int wn = (wave & 1) * 128;

  // ---- staging pointers ----
  const bf16_t* gA[2];
  const bf16_t* gB[4];
  bf16_t* lA0[2];
  bf16_t* lB0[4];
#pragma unroll
  for (int i = 0; i < 2; ++i) {
    int s = i * 256 + wave * 64 + lane;
    int row = s >> 2;
    int q = ((s & 3) - (s >> 3)) & 3;  // swizzled k-chunk this lane fetches
    gA[i] = A + (size_t)(bm + row) * K_IN + q * 8;
    lA0[i] = sA + (size_t)(i * 256 + wave * 64) * 8;  // wave-uniform base, buffer 0
  }
#pragma unroll
  for (int i = 0; i < 4; ++i) {
    int s = i * 256 + wave * 64 + lane;
    int row = s >> 2;
    int q = ((s & 3) - (s >> 3)) & 3;
    gB[i] = Bw + (size_t)(bn + row) * K_IN + q * 8;
    lB0[i] = sB + (size_t)(i * 256 + wave * 64) * 8;
  }

  // ---- fragment read pointers (buffer 0; buffer 1 = +BM*BK / +BN*BK elems) ----
  const int cofs = ((quad + (lr >> 1)) & 3) * 8;
  const bf16_t* fA[4];
  const bf16_t* fB[8];
#pragma unroll
  for (int i = 0; i < 4; ++i) fA[i] = sA + (wm + i * 16 + lr) * 32 + cofs;
#pragma unroll
  for (int j = 0; j < 8; ++j) fB[j] = sB + (wn + j * 16 + lr) * 32 + cofs;

  floatx4 acc[4][8];
#pragma unroll
  for (int i = 0; i < 4; ++i)
#pragma unroll
    for (int j = 0; j < 8; ++j) acc[i][j] = {0.f, 0.f, 0.f, 0.f};

#define STAGE(buf_ofsA, buf_ofsB)                                   \
  do {                                                              \
    async_copy16(gA[0], lA0[0] + (buf_ofsA));                       \
    async_copy16(gA[1], lA0[1] + (buf_ofsA));                       \
    async_copy16(gB[0], lB0[0] + (buf_ofsB));                       \
    async_copy16(gB[1], lB0[1] + (buf_ofsB));                       \
    async_copy16(gB[2], lB0[2] + (buf_ofsB));                       \
    async_copy16(gB[3], lB0[3] + (buf_ofsB));                       \
    gA[0] += BK; gA[1] += BK;                                       \
    gB[0] += BK; gB[1] += BK; gB[2] += BK; gB[3] += BK;             \
  } while (0)

#define COMPUTE(buf_ofsA, buf_ofsB)                                                   \
  do {                                                                                \
    bf16x8 a[4], b[8];                                                                \
    _Pragma("unroll") for (int i = 0; i < 4; ++i)                                     \
        a[i] = *(const bf16x8*)(fA[i] + (buf_ofsA));                                  \
    _Pragma("unroll") for (int j = 0; j < 8; ++j)                                     \
        b[j] = *(const bf16x8*)(fB[j] + (buf_ofsB));                                  \
    _Pragma("unroll") for (int i = 0; i < 4; ++i)                                     \
        _Pragma("unroll") for (int j = 0; j < 8; ++j)                                 \
            acc[i][j] = __builtin_amdgcn_mfma_f32_16x16x32_bf16(a[i], b[j],           \
                                                                acc[i][j], 0, 0, 0); \
  } while (0)

  STAGE(0, 0);  // k = 0 into buffer 0
  for (int it = 0; it < K_IN / BK; it += 2) {
    __syncthreads();              // drains stage(it) [flew during compute(it-1)]
    STAGE(BM * BK, BN * BK);      // k = it+1 into buffer 1
    COMPUTE(0, 0);                // compute k = it from buffer 0
    __syncthreads();              // drains stage(it+1) [flew during compute(it)]
    if (it + 2 < K_IN / BK) STAGE(0, 0);  // k = it+2 into buffer 0
    COMPUTE(BM * BK, BN * BK);    // compute k = it+1 from buffer 1
  }
#undef STAGE
#undef COMPUTE

  // Epilogue: row = quad*4 + reg (A side), col = lr (B side)
#pragma unroll
  for (int j = 0; j < 8; ++j) {
    int col = bn + wn + j * 16 + lr;
    float bb = bias[col];
#pragma unroll
    for (int i = 0; i < 4; ++i) {
      int row0 = bm + wm + i * 16 + quad * 4;
      floatx4 v = acc[i][j];
#pragma unroll
      for (int r = 0; r < 4; ++r)
        C[(size_t)(row0 + r) * N_OUT + col] = v[r] + bb;
    }
  }
}

// ---------------- fallback (workspace too small): fp32 path ----------------
__global__ __launch_bounds__(256) void lora_xa(const float* __restrict__ x,
                                               const float* __restrict__ lA,
                                               const float* __restrict__ scale_p,
                                               float* __restrict__ t) {
  int m = blockIdx.x;
  int r = threadIdx.x & 15;
  int kcn = threadIdx.x >> 4;
  float acc = 0.f;
  const float* xr = x + (size_t)m * K_IN + kcn * 256;
  const float* ar = lA + (size_t)r * K_IN + kcn * 256;
  for (int k = 0; k < 256; k += 4) {
    float4 xv = *(const float4*)(xr + k);
    float4 av = *(const float4*)(ar + k);
    acc += xv.x * av.x + xv.y * av.y + xv.z * av.z + xv.w * av.w;
  }
  __shared__ float s[256];
  s[threadIdx.x] = acc;
  __syncthreads();
  if (threadIdx.x < 16) {
    float v = 0.f;
    for (int i = 0; i < 16; ++i) v += s[threadIdx.x + i * 16];
    t[(size_t)m * 16 + threadIdx.x] = v * (*scale_p);
  }
}

__global__ __launch_bounds__(256) void gemm_f32_fb(const float* __restrict__ X,
                                                   const float* __restrict__ W,
                                                   const float* __restrict__ bias,
                                                   const float* __restrict__ t,
                                                   const float* __restrict__ lB,
                                                   float* __restrict__ C) {
  __shared__ float sX[64][17];
  __shared__ float sW[64][17];
  int tid = threadIdx.x;
  int tx = tid & 15, ty = tid >> 4;
  int m0 = blockIdx.y * 64, n0 = blockIdx.x * 64;
  int lrow = tid >> 2, lcol = (tid & 3) * 4;
  float acc[4][4] = {};
  for (int k0 = 0; k0 < K_IN; k0 += 16) {
    __syncthreads();
    float4 xv = *(const float4*)(X + (size_t)(m0 + lrow) * K_IN + k0 + lcol);
    float4 wv = *(const float4*)(W + (size_t)(n0 + lrow) * K_IN + k0 + lcol);
    sX[lrow][lcol + 0] = xv.x; sX[lrow][lcol + 1] = xv.y;
    sX[lrow][lcol + 2] = xv.z; sX[lrow][lcol + 3] = xv.w;
    sW[lrow][lcol + 0] = wv.x; sW[lrow][lcol + 1] = wv.y;
    sW[lrow][lcol + 2] = wv.z; sW[lrow][lcol + 3] = wv.w;
    __syncthreads();
#pragma unroll
    for (int kk = 0; kk < 16; ++kk) {
      float xr[4], wr[4];
#pragma unroll
      for (int i = 0; i < 4; ++i) { xr[i] = sX[ty * 4 + i][kk]; wr[i] = sW[tx * 4 + i][kk]; }
#pragma unroll
      for (int i = 0; i < 4; ++i)
#pragma unroll
        for (int j = 0; j < 4; ++j) acc[i][j] += xr[i] * wr[j];
    }
  }
  for (int j = 0; j < 4; ++j) {
    int n = n0 + tx * 4 + j;
    float bb = bias[n];
    for (int i = 0; i < 4; ++i) {
      int m = m0 + ty * 4 + i;
      float l = 0.f;
      for (int r = 0; r < R_LORA; ++r) l += t[(size_t)m * 16 + r] * lB[(size_t)n * 16 + r];
      C[(size_t)m * N_OUT + n] = acc[i][j] + bb + l;
    }
  }
}

extern "C" void kernel_launch(void* const* d_in, const int* in_sizes, int n_in,
                              void* d_out, int out_size, void* d_ws, size_t ws_size,
                              hipStream_t stream) {
  const float* x     = (const float*)d_in[0];
  const float* W     = (const float*)d_in[1];
  const float* bias  = (const float*)d_in[2];
  const float* lB    = (const float*)d_in[3];
  const float* lA    = (const float*)d_in[4];
  const float* scale = (const float*)d_in[5];
  float* out = (float*)d_out;

  const size_t x_bytes = (size_t)M_TOK * K_IN * sizeof(bf16_t);  // 64 MB
  const size_t w_bytes = (size_t)N_OUT * K_IN * sizeof(bf16_t);  // 32 MB

  if (ws_size >= x_bytes + w_bytes) {
    bf16_t* xb = (bf16_t*)d_ws;
    bf16_t* wb = (bf16_t*)((char*)d_ws + x_bytes);
    cast_x_kernel<<<(M_TOK * K_IN / 4) / 256, 256, 0, stream>>>(x, xb);
    make_weff<<<dim3(K_IN / 1024, N_OUT / 32), 256, 0, stream>>>(W, lB, lA, scale, wb);
    gemm_bt<<<dim3(N_OUT / BN, M_TOK / BM), 256, 0, stream>>>(xb, wb, bias, out);
  } else {
    float* t = (float*)d_ws;
    lora_xa<<<M_TOK, 256, 0, stream>>>(x, lA, scale, t);
    gemm_f32_fb<<<dim3(N_OUT / 64, M_TOK / 64), 256, 0, stream>>>(x, W, bias, t, lB, out);
  }
}